// Round 3
// baseline (574.559 us; speedup 1.0000x reference)
//
#include <hip/hip_runtime.h>
#include <hip/hip_bf16.h>

#define NB 16
#define NC 64

// ---------------------------------------------------------------------------
// K1: LL band of Haar DWT of x: (B,C,256,256) -> (B,C,128,128). Pure stream.
// ---------------------------------------------------------------------------
__global__ __launch_bounds__(256) void ll_kernel(
    const float* __restrict__ in, float* __restrict__ ll)
{
    int t = blockIdx.x * 256 + threadIdx.x;   // NB*NC*128*64 threads
    int jp  = t & 63;                          // output column pair
    int i   = (t >> 6) & 127;                  // output row
    int img = t >> 13;                         // b*NC+c
    size_t ib = (size_t)img * 65536;
    float4 a = *(const float4*)(in + ib + (size_t)(2 * i) * 256 + 4 * jp);
    float4 b = *(const float4*)(in + ib + (size_t)(2 * i + 1) * 256 + 4 * jp);
    float2 o;
    o.x = 0.5f * (a.x + a.y + b.x + b.y);
    o.y = 0.5f * (a.z + a.w + b.z + b.w);
    *(float2*)(ll + (size_t)img * 16384 + (size_t)i * 128 + 2 * jp) = o;
}

// ---------------------------------------------------------------------------
// K2/K3: fused Haar DWT + depthwise 3x3 conv (SAME, zero pad) + scale.
// in (B,C,H,H) fp32 -> t (B,C,4,H/2,H/2) fp32, curn (B,C,H/2,H/2) = pre-conv LL.
// 32x32 half-res outputs per block.
// ---------------------------------------------------------------------------
template <int H>
__global__ __launch_bounds__(256) void dwt_conv_kernel(
    const float* __restrict__ in, const float* __restrict__ ww,
    const float* __restrict__ wsc, float* __restrict__ t_out,
    float* __restrict__ curn)
{
    constexpr int H2 = H / 2;
    constexpr int TX = H2 / 32;
    const int tile = blockIdx.x;
    const int c = blockIdx.y, b = blockIdx.z;
    const int ty = tile / TX, tx = tile % TX;
    const int oy0 = ty * 32, ox0 = tx * 32;
    const int tid = threadIdx.x;

    __shared__ float sIn[68][69];
    __shared__ float sDwt[4][34][34];
    __shared__ float sW[4][9];
    __shared__ float sS[4];

    if (tid < 36) sW[tid / 9][tid % 9] = ww[(c * 4 + tid / 9) * 9 + tid % 9];
    else if (tid < 40) sS[tid - 36] = wsc[c * 4 + tid - 36];

    const size_t ibase = (size_t)(b * NC + c) * H * H;
    const int iy0 = 2 * oy0 - 2, ix0 = 2 * ox0 - 2;
    for (int idx = tid; idx < 68 * 68; idx += 256) {
        int r = idx / 68, cc = idx - r * 68;
        int gy = iy0 + r, gx = ix0 + cc;
        float v = 0.f;
        if ((unsigned)gy < (unsigned)H && (unsigned)gx < (unsigned)H)
            v = in[ibase + (size_t)gy * H + gx];
        sIn[r][cc] = v;
    }
    __syncthreads();

    for (int idx = tid; idx < 34 * 34; idx += 256) {
        int dy = idx / 34, dx = idx - dy * 34;
        float a = sIn[2 * dy][2 * dx],     e = sIn[2 * dy][2 * dx + 1];
        float f = sIn[2 * dy + 1][2 * dx], g = sIn[2 * dy + 1][2 * dx + 1];
        float s0 = a + e, s1 = f + g, d0 = a - e, d1 = f - g;
        sDwt[0][dy][dx] = 0.5f * (s0 + s1);   // LL
        sDwt[1][dy][dx] = 0.5f * (s0 - s1);   // row-diff
        sDwt[2][dy][dx] = 0.5f * (d0 + d1);   // col-diff
        sDwt[3][dy][dx] = 0.5f * (d0 - d1);   // HH
    }
    __syncthreads();

    const size_t tbase = (size_t)(b * NC + c) * 4 * H2 * H2;
    const size_t cbase = (size_t)(b * NC + c) * H2 * H2;
    for (int idx = tid; idx < 1024; idx += 256) {
        int y = idx >> 5, x = idx & 31;
        size_t o = (size_t)(oy0 + y) * H2 + (ox0 + x);
#pragma unroll
        for (int k = 0; k < 4; ++k) {
            float acc = 0.f;
#pragma unroll
            for (int r = 0; r < 3; ++r)
#pragma unroll
                for (int s = 0; s < 3; ++s)
                    acc += sDwt[k][y + r][x + s] * sW[k][3 * r + s];
            t_out[tbase + (size_t)k * H2 * H2 + o] = acc * sS[k];
        }
        if (curn) curn[cbase + o] = sDwt[0][y + 1][x + 1];
    }
}

// ---------------------------------------------------------------------------
// K4/K5: IDWT. t (B,C,4,HW,HW) [LL += nxt] -> out (B,C,2HW,2HW)
// ---------------------------------------------------------------------------
template <int HW>
__global__ __launch_bounds__(256) void idwt_kernel(
    const float* __restrict__ t, const float* __restrict__ nxt_in,
    float* __restrict__ out)
{
    int idx = blockIdx.x * 256 + threadIdx.x;
    int j = idx & (HW - 1);
    int i = (idx / HW) & (HW - 1);
    int img = idx / (HW * HW);
    size_t pb = (size_t)img * 4 * HW * HW + (size_t)i * HW + j;
    float k0 = t[pb];
    float k1 = t[pb + HW * HW];
    float k2 = t[pb + 2 * HW * HW];
    float k3 = t[pb + 3 * HW * HW];
    if (nxt_in) k0 += nxt_in[(size_t)img * HW * HW + (size_t)i * HW + j];
    size_t ob = (size_t)img * 4 * HW * HW + (size_t)(2 * i) * (2 * HW) + 2 * j;
    *(float2*)(out + ob) = make_float2(0.5f * (k0 + k1 + k2 + k3),
                                       0.5f * (k0 + k1 - k2 - k3));
    *(float2*)(out + ob + 2 * HW) = make_float2(0.5f * (k0 - k1 + k2 - k3),
                                                0.5f * (k0 - k1 - k2 + k3));
}

// ---------------------------------------------------------------------------
// K6: final fuse. Recomputes level-0 DWT + band conv from the staged x tile,
// adds nxt1 to LL, IDWTs, adds base conv path, writes unnormalized y (fp32)
// into d_out, and emits per-block BN partial sums (deterministic).
// Block: 64x64 output pixels, 256 threads.
// ---------------------------------------------------------------------------
__global__ __launch_bounds__(256) void final_fuse_kernel(
    const float* __restrict__ x, const float* __restrict__ nxt1,
    const float* __restrict__ bw, const float* __restrict__ bb,
    const float* __restrict__ bs, const float* __restrict__ ww0,
    const float* __restrict__ ws0,
    float* __restrict__ yout, float2* __restrict__ partials)
{
    const int tile = blockIdx.x, c = blockIdx.y, b = blockIdx.z;
    const int ty = tile >> 2, tx = tile & 3;
    const int oy0 = ty * 64, ox0 = tx * 64;
    const int hy0 = ty * 32, hx0 = tx * 32;
    const int tid = threadIdx.x;

    __shared__ float sIn[68][69];
    __shared__ float sDwt[4][34][34];
    __shared__ float sWW[4][9];
    __shared__ float sWS[4];
    __shared__ float sWB[9];
    __shared__ float rS[256], rQ[256];

    if (tid < 36) sWW[tid / 9][tid % 9] = ww0[(c * 4 + tid / 9) * 9 + tid % 9];
    else if (tid < 40) sWS[tid - 36] = ws0[c * 4 + tid - 36];
    else if (tid < 49) sWB[tid - 40] = bw[c * 9 + tid - 40];

    const float bias = bb[c], scale = bs[c];

    const size_t xb = (size_t)(b * NC + c) * 65536;
    for (int idx = tid; idx < 68 * 68; idx += 256) {
        int r = idx / 68, cc = idx - r * 68;
        int gy = oy0 - 2 + r, gx = ox0 - 2 + cc;
        float v = 0.f;
        if ((unsigned)gy < 256u && (unsigned)gx < 256u)
            v = x[xb + (size_t)gy * 256 + gx];
        sIn[r][cc] = v;
    }
    __syncthreads();

    for (int idx = tid; idx < 34 * 34; idx += 256) {
        int dy = idx / 34, dx = idx - dy * 34;
        float a = sIn[2 * dy][2 * dx],     e = sIn[2 * dy][2 * dx + 1];
        float f = sIn[2 * dy + 1][2 * dx], g = sIn[2 * dy + 1][2 * dx + 1];
        float s0 = a + e, s1 = f + g, d0 = a - e, d1 = f - g;
        sDwt[0][dy][dx] = 0.5f * (s0 + s1);
        sDwt[1][dy][dx] = 0.5f * (s0 - s1);
        sDwt[2][dy][dx] = 0.5f * (d0 + d1);
        sDwt[3][dy][dx] = 0.5f * (d0 - d1);
    }
    __syncthreads();

    const size_t n1b = (size_t)(b * NC + c) * 16384;
    float lsum = 0.f, lss = 0.f;
    for (int qidx = tid; qidx < 1024; qidx += 256) {
        int qi = qidx >> 5, qj = qidx & 31;
        float kk[4];
#pragma unroll
        for (int k = 0; k < 4; ++k) {
            float acc = 0.f;
#pragma unroll
            for (int r = 0; r < 3; ++r)
#pragma unroll
                for (int s = 0; s < 3; ++s)
                    acc += sDwt[k][qi + r][qj + s] * sWW[k][3 * r + s];
            kk[k] = acc * sWS[k];
        }
        kk[0] += nxt1[n1b + (size_t)(hy0 + qi) * 128 + (hx0 + qj)];
        float vv[2][2];
        vv[0][0] = 0.5f * (kk[0] + kk[1] + kk[2] + kk[3]);
        vv[0][1] = 0.5f * (kk[0] + kk[1] - kk[2] - kk[3]);
        vv[1][0] = 0.5f * (kk[0] - kk[1] + kk[2] - kk[3]);
        vv[1][1] = 0.5f * (kk[0] - kk[1] - kk[2] + kk[3]);
        int yl = 2 * qi, xl = 2 * qj;
#pragma unroll
        for (int p = 0; p < 2; ++p) {
            float v2[2];
#pragma unroll
            for (int q = 0; q < 2; ++q) {
                float acc = 0.f;
#pragma unroll
                for (int r = 0; r < 3; ++r)
#pragma unroll
                    for (int s = 0; s < 3; ++s)
                        acc += sIn[yl + p + r + 1][xl + q + s + 1] * sWB[3 * r + s];
                float val = (acc + bias) * scale + vv[p][q];
                lsum += val;
                lss += val * val;
                v2[q] = val;
            }
            *(float2*)(yout + xb + (size_t)(oy0 + yl + p) * 256 + (ox0 + xl)) =
                make_float2(v2[0], v2[1]);
        }
    }
    rS[tid] = lsum;
    rQ[tid] = lss;
    __syncthreads();
    for (int off = 128; off > 0; off >>= 1) {
        if (tid < off) { rS[tid] += rS[tid + off]; rQ[tid] += rQ[tid + off]; }
        __syncthreads();
    }
    if (tid == 0)
        partials[c * 256 + b * 16 + tile] = make_float2(rS[0], rQ[0]);
}

// ---------------------------------------------------------------------------
// K7: per-channel BN stats -> (a,b) scale/shift. 64 blocks x 256 threads.
// ---------------------------------------------------------------------------
__global__ __launch_bounds__(256) void stats_kernel(
    const float2* __restrict__ partials, const float* __restrict__ gamma,
    const float* __restrict__ beta, float2* __restrict__ ab)
{
    const int c = blockIdx.x;
    const int tid = threadIdx.x;
    __shared__ float s1[256], s2[256];
    float2 p = partials[c * 256 + tid];
    s1[tid] = p.x;
    s2[tid] = p.y;
    __syncthreads();
    for (int off = 128; off > 0; off >>= 1) {
        if (tid < off) { s1[tid] += s1[tid + off]; s2[tid] += s2[tid + off]; }
        __syncthreads();
    }
    if (tid == 0) {
        const float N = (float)NB * 65536.0f;
        float mean = s1[0] / N;
        float var = s2[0] / N - mean * mean;
        float inv = rsqrtf(var + 1e-5f);
        float a = gamma[c] * inv;
        ab[c] = make_float2(a, beta[c] - mean * a);
    }
}

// ---------------------------------------------------------------------------
// K8: in-place normalize + ReLU on d_out (fp32), float4 vectorized.
// ---------------------------------------------------------------------------
__global__ __launch_bounds__(256) void norm_inplace_kernel(
    float* __restrict__ y, const float2* __restrict__ ab)
{
    const long total4 = (long)NB * NC * 65536 / 4;
    const long stride = (long)gridDim.x * 256;
    for (long i = blockIdx.x * 256L + threadIdx.x; i < total4; i += stride) {
        long e = i * 4;
        int c = (int)((e >> 16) & (NC - 1));
        float2 s = ab[c];
        float4 v = *(const float4*)(y + e);
        v.x = fmaxf(v.x * s.x + s.y, 0.f);
        v.y = fmaxf(v.y * s.x + s.y, 0.f);
        v.z = fmaxf(v.z * s.x + s.y, 0.f);
        v.w = fmaxf(v.w * s.x + s.y, 0.f);
        *(float4*)(y + e) = v;
    }
}

extern "C" void kernel_launch(void* const* d_in, const int* in_sizes, int n_in,
                              void* d_out, int out_size, void* d_ws, size_t ws_size,
                              hipStream_t stream)
{
    const float* x    = (const float*)d_in[0];
    const float* bw   = (const float*)d_in[1];
    const float* bb   = (const float*)d_in[2];
    const float* bs   = (const float*)d_in[3];
    const float* ww0  = (const float*)d_in[4];
    const float* ww1  = (const float*)d_in[5];
    const float* ww2  = (const float*)d_in[6];
    const float* ws0  = (const float*)d_in[7];
    const float* ws1  = (const float*)d_in[8];
    const float* ws2  = (const float*)d_in[9];
    const float* gamma = (const float*)d_in[10];
    const float* beta  = (const float*)d_in[11];

    char* w = (char*)d_ws;
    size_t off = 0;
    auto alloc = [&](size_t bytes) {
        char* p = w + off;
        off = (off + bytes + 255) & ~(size_t)255;
        return (void*)p;
    };
    float* cur1    = (float*)alloc((size_t)NB * NC * 128 * 128 * 4);     // 67.1 MB (reused as nxt1)
    float* t1      = (float*)alloc((size_t)NB * NC * 4 * 64 * 64 * 4);   // 67.1 MB
    float* cur2    = (float*)alloc((size_t)NB * NC * 64 * 64 * 4);       // 16.8 MB
    float* t2      = (float*)alloc((size_t)NB * NC * 4 * 32 * 32 * 4);   // 16.8 MB
    float* nxt2    = (float*)alloc((size_t)NB * NC * 64 * 64 * 4);       // 16.8 MB
    float2* partials = (float2*)alloc((size_t)16384 * 8);
    float2* ab       = (float2*)alloc((size_t)64 * 8);
    float* nxt1 = cur1;   // cur1 dead after K2; idwt<64> writes nxt1 here

    float* yb = (float*)d_out;  // fp32 staging in d_out (output dtype = fp32)

    // K1: x -> cur1 (LL only; level-0 bands recomputed in K6)
    ll_kernel<<<dim3(NB * NC * 128 * 64 / 256), 256, 0, stream>>>(x, cur1);
    // K2: level 1
    dwt_conv_kernel<128><<<dim3(4, NC, NB), 256, 0, stream>>>(cur1, ww1, ws1, t1, cur2);
    // K3: level 2
    dwt_conv_kernel<64><<<dim3(1, NC, NB), 256, 0, stream>>>(cur2, ww2, ws2, t2, nullptr);
    // K4: recon level 2 -> nxt2 (64x64)
    idwt_kernel<32><<<dim3(NB * NC * 32 * 32 / 256), 256, 0, stream>>>(t2, nullptr, nxt2);
    // K5: recon level 1 -> nxt1 (128x128), reuses cur1's storage
    idwt_kernel<64><<<dim3(NB * NC * 64 * 64 / 256), 256, 0, stream>>>(t1, nxt2, nxt1);
    // K6: base conv + level-0 dwt/conv/idwt + y (fp32 into d_out) + partials
    final_fuse_kernel<<<dim3(16, NC, NB), 256, 0, stream>>>(x, nxt1, bw, bb, bs, ww0, ws0, yb, partials);
    // K7: BN stats
    stats_kernel<<<dim3(64), 256, 0, stream>>>(partials, gamma, beta, ab);
    // K8: normalize + relu in place
    norm_inplace_kernel<<<dim3(2048), 256, 0, stream>>>(yb, ab);
}

// Round 4
// 485.323 us; speedup vs baseline: 1.1839x; 1.1839x over previous
//
#include <hip/hip_runtime.h>
#include <hip/hip_bf16.h>

#define NB 16
#define NC 64

// ---------------------------------------------------------------------------
// K1: LL band of Haar DWT of x: (B,C,256,256) -> (B,C,128,128). Pure stream.
// ---------------------------------------------------------------------------
__global__ __launch_bounds__(256) void ll_kernel(
    const float* __restrict__ in, float* __restrict__ ll)
{
    int t = blockIdx.x * 256 + threadIdx.x;   // NB*NC*128*64 threads
    int jp  = t & 63;                          // output column pair
    int i   = (t >> 6) & 127;                  // output row
    int img = t >> 13;                         // b*NC+c
    size_t ib = (size_t)img * 65536;
    float4 a = *(const float4*)(in + ib + (size_t)(2 * i) * 256 + 4 * jp);
    float4 b = *(const float4*)(in + ib + (size_t)(2 * i + 1) * 256 + 4 * jp);
    float2 o;
    o.x = 0.5f * (a.x + a.y + b.x + b.y);
    o.y = 0.5f * (a.z + a.w + b.z + b.w);
    *(float2*)(ll + (size_t)img * 16384 + (size_t)i * 128 + 2 * jp) = o;
}

// ---------------------------------------------------------------------------
// K2/K3: fused Haar DWT + depthwise 3x3 conv (SAME) + scale, register-DWT.
// Per thread: 6x6 sIn patch -> 9 DWT positions in regs -> 4 band convs.
// in (B,C,H,H) -> t (B,C,4,H/2,H/2), curn = pre-conv LL.
// ---------------------------------------------------------------------------
template <int H>
__global__ __launch_bounds__(256) void dwt_conv_kernel(
    const float* __restrict__ in, const float* __restrict__ ww,
    const float* __restrict__ wsc, float* __restrict__ t_out,
    float* __restrict__ curn)
{
    constexpr int H2 = H / 2;
    constexpr int TX = H2 / 32;
    const int tile = blockIdx.x;
    const int c = blockIdx.y, b = blockIdx.z;
    const int ty = tile / TX, tx = tile % TX;
    const int oy0 = ty * 32, ox0 = tx * 32;
    const int tid = threadIdx.x;

    __shared__ float sIn[68][70];   // stride 70 floats = 280 B (8B aligned rows)

    float w[4][9], sc[4];
#pragma unroll
    for (int k = 0; k < 4; ++k) {
#pragma unroll
        for (int i = 0; i < 9; ++i) w[k][i] = ww[(c * 4 + k) * 9 + i];
        sc[k] = 0.5f * wsc[c * 4 + k];   // fold DWT 0.5 into scale
    }

    const size_t ibase = (size_t)(b * NC + c) * H * H;
    const int iy0 = 2 * oy0 - 2, ix0 = 2 * ox0 - 2;
    for (int idx = tid; idx < 68 * 68; idx += 256) {
        int r = idx / 68, cc = idx - r * 68;
        int gy = iy0 + r, gx = ix0 + cc;
        float v = 0.f;
        if ((unsigned)gy < (unsigned)H && (unsigned)gx < (unsigned)H)
            v = in[ibase + (size_t)gy * H + gx];
        sIn[r][cc] = v;
    }
    __syncthreads();

    const size_t tbase = (size_t)(b * NC + c) * 4 * H2 * H2;
    const size_t cbase = (size_t)(b * NC + c) * H2 * H2;
    for (int qidx = tid; qidx < 1024; qidx += 256) {
        int qi = qidx >> 5, qj = qidx & 31;
        float P[6][6];
#pragma unroll
        for (int r = 0; r < 6; ++r) {
            const float2* rp = (const float2*)&sIn[2 * qi + r][2 * qj];
            float2 p0 = rp[0], p1 = rp[1], p2 = rp[2];
            P[r][0] = p0.x; P[r][1] = p0.y; P[r][2] = p1.x;
            P[r][3] = p1.y; P[r][4] = p2.x; P[r][5] = p2.y;
        }
        float kk0 = 0.f, kk1 = 0.f, kk2 = 0.f, kk3 = 0.f, llc = 0.f;
#pragma unroll
        for (int r = 0; r < 3; ++r)
#pragma unroll
            for (int s = 0; s < 3; ++s) {
                float a = P[2*r][2*s],   e = P[2*r][2*s+1];
                float f = P[2*r+1][2*s], g = P[2*r+1][2*s+1];
                float s0 = a + e, s1 = f + g, d0 = a - e, d1 = f - g;
                float b0 = s0 + s1;
                kk0 += w[0][3*r+s] * b0;
                kk1 += w[1][3*r+s] * (s0 - s1);
                kk2 += w[2][3*r+s] * (d0 + d1);
                kk3 += w[3][3*r+s] * (d0 - d1);
                if (r == 1 && s == 1) llc = 0.5f * b0;
            }
        size_t o = (size_t)(oy0 + qi) * H2 + (ox0 + qj);
        t_out[tbase + o]                        = kk0 * sc[0];
        t_out[tbase + (size_t)H2 * H2 + o]      = kk1 * sc[1];
        t_out[tbase + (size_t)2 * H2 * H2 + o]  = kk2 * sc[2];
        t_out[tbase + (size_t)3 * H2 * H2 + o]  = kk3 * sc[3];
        if (curn) curn[cbase + o] = llc;
    }
}

// ---------------------------------------------------------------------------
// K4/K5: IDWT. t (B,C,4,HW,HW) [LL += nxt] -> out (B,C,2HW,2HW)
// ---------------------------------------------------------------------------
template <int HW>
__global__ __launch_bounds__(256) void idwt_kernel(
    const float* __restrict__ t, const float* __restrict__ nxt_in,
    float* __restrict__ out)
{
    int idx = blockIdx.x * 256 + threadIdx.x;
    int j = idx & (HW - 1);
    int i = (idx / HW) & (HW - 1);
    int img = idx / (HW * HW);
    size_t pb = (size_t)img * 4 * HW * HW + (size_t)i * HW + j;
    float k0 = t[pb];
    float k1 = t[pb + HW * HW];
    float k2 = t[pb + 2 * HW * HW];
    float k3 = t[pb + 3 * HW * HW];
    if (nxt_in) k0 += nxt_in[(size_t)img * HW * HW + (size_t)i * HW + j];
    size_t ob = (size_t)img * 4 * HW * HW + (size_t)(2 * i) * (2 * HW) + 2 * j;
    *(float2*)(out + ob) = make_float2(0.5f * (k0 + k1 + k2 + k3),
                                       0.5f * (k0 + k1 - k2 - k3));
    *(float2*)(out + ob + 2 * HW) = make_float2(0.5f * (k0 - k1 + k2 - k3),
                                                0.5f * (k0 - k1 - k2 + k3));
}

// ---------------------------------------------------------------------------
// K6: final fuse, register-DWT version. Per thread-quad: 6x6 sIn patch ->
// band convs + base conv in regs -> IDWT -> y (fp32 in d_out) + BN partials.
// Block: 64x64 output pixels, 256 threads.
// ---------------------------------------------------------------------------
__global__ __launch_bounds__(256) void final_fuse_kernel(
    const float* __restrict__ x, const float* __restrict__ nxt1,
    const float* __restrict__ bw, const float* __restrict__ bb,
    const float* __restrict__ bs, const float* __restrict__ ww0,
    const float* __restrict__ ws0,
    float* __restrict__ yout, float2* __restrict__ partials)
{
    const int tile = blockIdx.x, c = blockIdx.y, b = blockIdx.z;
    const int ty = tile >> 2, tx = tile & 3;
    const int oy0 = ty * 64, ox0 = tx * 64;
    const int hy0 = ty * 32, hx0 = tx * 32;
    const int tid = threadIdx.x;

    __shared__ float sIn[68][70];
    __shared__ float rS[256], rQ[256];

    float w[4][9], sc[4], wb[9];
#pragma unroll
    for (int k = 0; k < 4; ++k) {
#pragma unroll
        for (int i = 0; i < 9; ++i) w[k][i] = ww0[(c * 4 + k) * 9 + i];
        sc[k] = 0.5f * ws0[c * 4 + k];
    }
#pragma unroll
    for (int i = 0; i < 9; ++i) wb[i] = bw[c * 9 + i];
    const float bias = bb[c], scale = bs[c];

    const size_t xb = (size_t)(b * NC + c) * 65536;
    for (int idx = tid; idx < 68 * 68; idx += 256) {
        int r = idx / 68, cc = idx - r * 68;
        int gy = oy0 - 2 + r, gx = ox0 - 2 + cc;
        float v = 0.f;
        if ((unsigned)gy < 256u && (unsigned)gx < 256u)
            v = x[xb + (size_t)gy * 256 + gx];
        sIn[r][cc] = v;
    }
    __syncthreads();

    const size_t n1b = (size_t)(b * NC + c) * 16384;
    float lsum = 0.f, lss = 0.f;
    for (int qidx = tid; qidx < 1024; qidx += 256) {
        int qi = qidx >> 5, qj = qidx & 31;
        float P[6][6];
#pragma unroll
        for (int r = 0; r < 6; ++r) {
            const float2* rp = (const float2*)&sIn[2 * qi + r][2 * qj];
            float2 p0 = rp[0], p1 = rp[1], p2 = rp[2];
            P[r][0] = p0.x; P[r][1] = p0.y; P[r][2] = p1.x;
            P[r][3] = p1.y; P[r][4] = p2.x; P[r][5] = p2.y;
        }
        // 4 band convs over register DWT
        float kk0 = 0.f, kk1 = 0.f, kk2 = 0.f, kk3 = 0.f;
#pragma unroll
        for (int r = 0; r < 3; ++r)
#pragma unroll
            for (int s = 0; s < 3; ++s) {
                float a = P[2*r][2*s],   e = P[2*r][2*s+1];
                float f = P[2*r+1][2*s], g = P[2*r+1][2*s+1];
                float s0 = a + e, s1 = f + g, d0 = a - e, d1 = f - g;
                kk0 += w[0][3*r+s] * (s0 + s1);
                kk1 += w[1][3*r+s] * (s0 - s1);
                kk2 += w[2][3*r+s] * (d0 + d1);
                kk3 += w[3][3*r+s] * (d0 - d1);
            }
        kk0 = kk0 * sc[0] + nxt1[n1b + (size_t)(hy0 + qi) * 128 + (hx0 + qj)];
        kk1 *= sc[1];
        kk2 *= sc[2];
        kk3 *= sc[3];
        float vv[2][2];
        vv[0][0] = 0.5f * (kk0 + kk1 + kk2 + kk3);
        vv[0][1] = 0.5f * (kk0 + kk1 - kk2 - kk3);
        vv[1][0] = 0.5f * (kk0 - kk1 + kk2 - kk3);
        vv[1][1] = 0.5f * (kk0 - kk1 - kk2 + kk3);
        int yl = 2 * qi, xl = 2 * qj;
#pragma unroll
        for (int p = 0; p < 2; ++p) {
            float v2[2];
#pragma unroll
            for (int q = 0; q < 2; ++q) {
                float acc = 0.f;
#pragma unroll
                for (int r = 0; r < 3; ++r)
#pragma unroll
                    for (int s = 0; s < 3; ++s)
                        acc += P[p + r + 1][q + s + 1] * wb[3 * r + s];
                float val = (acc + bias) * scale + vv[p][q];
                lsum += val;
                lss += val * val;
                v2[q] = val;
            }
            *(float2*)(yout + xb + (size_t)(oy0 + yl + p) * 256 + (ox0 + xl)) =
                make_float2(v2[0], v2[1]);
        }
    }
    rS[tid] = lsum;
    rQ[tid] = lss;
    __syncthreads();
    for (int off = 128; off > 0; off >>= 1) {
        if (tid < off) { rS[tid] += rS[tid + off]; rQ[tid] += rQ[tid + off]; }
        __syncthreads();
    }
    if (tid == 0)
        partials[c * 256 + b * 16 + tile] = make_float2(rS[0], rQ[0]);
}

// ---------------------------------------------------------------------------
// K7: per-channel BN stats -> (a,b) scale/shift. 64 blocks x 256 threads.
// ---------------------------------------------------------------------------
__global__ __launch_bounds__(256) void stats_kernel(
    const float2* __restrict__ partials, const float* __restrict__ gamma,
    const float* __restrict__ beta, float2* __restrict__ ab)
{
    const int c = blockIdx.x;
    const int tid = threadIdx.x;
    __shared__ float s1[256], s2[256];
    float2 p = partials[c * 256 + tid];
    s1[tid] = p.x;
    s2[tid] = p.y;
    __syncthreads();
    for (int off = 128; off > 0; off >>= 1) {
        if (tid < off) { s1[tid] += s1[tid + off]; s2[tid] += s2[tid + off]; }
        __syncthreads();
    }
    if (tid == 0) {
        const float N = (float)NB * 65536.0f;
        float mean = s1[0] / N;
        float var = s2[0] / N - mean * mean;
        float inv = rsqrtf(var + 1e-5f);
        float a = gamma[c] * inv;
        ab[c] = make_float2(a, beta[c] - mean * a);
    }
}

// ---------------------------------------------------------------------------
// K8: in-place normalize + ReLU on d_out (fp32), float4 vectorized.
// ---------------------------------------------------------------------------
__global__ __launch_bounds__(256) void norm_inplace_kernel(
    float* __restrict__ y, const float2* __restrict__ ab)
{
    const long total4 = (long)NB * NC * 65536 / 4;
    const long stride = (long)gridDim.x * 256;
    for (long i = blockIdx.x * 256L + threadIdx.x; i < total4; i += stride) {
        long e = i * 4;
        int c = (int)((e >> 16) & (NC - 1));
        float2 s = ab[c];
        float4 v = *(const float4*)(y + e);
        v.x = fmaxf(v.x * s.x + s.y, 0.f);
        v.y = fmaxf(v.y * s.x + s.y, 0.f);
        v.z = fmaxf(v.z * s.x + s.y, 0.f);
        v.w = fmaxf(v.w * s.x + s.y, 0.f);
        *(float4*)(y + e) = v;
    }
}

extern "C" void kernel_launch(void* const* d_in, const int* in_sizes, int n_in,
                              void* d_out, int out_size, void* d_ws, size_t ws_size,
                              hipStream_t stream)
{
    const float* x    = (const float*)d_in[0];
    const float* bw   = (const float*)d_in[1];
    const float* bb   = (const float*)d_in[2];
    const float* bs   = (const float*)d_in[3];
    const float* ww0  = (const float*)d_in[4];
    const float* ww1  = (const float*)d_in[5];
    const float* ww2  = (const float*)d_in[6];
    const float* ws0  = (const float*)d_in[7];
    const float* ws1  = (const float*)d_in[8];
    const float* ws2  = (const float*)d_in[9];
    const float* gamma = (const float*)d_in[10];
    const float* beta  = (const float*)d_in[11];

    char* w = (char*)d_ws;
    size_t off = 0;
    auto alloc = [&](size_t bytes) {
        char* p = w + off;
        off = (off + bytes + 255) & ~(size_t)255;
        return (void*)p;
    };
    float* cur1    = (float*)alloc((size_t)NB * NC * 128 * 128 * 4);     // 67.1 MB (reused as nxt1)
    float* t1      = (float*)alloc((size_t)NB * NC * 4 * 64 * 64 * 4);   // 67.1 MB
    float* cur2    = (float*)alloc((size_t)NB * NC * 64 * 64 * 4);       // 16.8 MB
    float* t2      = (float*)alloc((size_t)NB * NC * 4 * 32 * 32 * 4);   // 16.8 MB
    float* nxt2    = (float*)alloc((size_t)NB * NC * 64 * 64 * 4);       // 16.8 MB
    float2* partials = (float2*)alloc((size_t)16384 * 8);
    float2* ab       = (float2*)alloc((size_t)64 * 8);
    float* nxt1 = cur1;   // cur1 dead after K2; idwt<64> writes nxt1 here

    float* yb = (float*)d_out;  // fp32 staging in d_out (output dtype = fp32)

    // K1: x -> cur1 (LL only; level-0 bands recomputed in K6)
    ll_kernel<<<dim3(NB * NC * 128 * 64 / 256), 256, 0, stream>>>(x, cur1);
    // K2: level 1
    dwt_conv_kernel<128><<<dim3(4, NC, NB), 256, 0, stream>>>(cur1, ww1, ws1, t1, cur2);
    // K3: level 2
    dwt_conv_kernel<64><<<dim3(1, NC, NB), 256, 0, stream>>>(cur2, ww2, ws2, t2, nullptr);
    // K4: recon level 2 -> nxt2 (64x64)
    idwt_kernel<32><<<dim3(NB * NC * 32 * 32 / 256), 256, 0, stream>>>(t2, nullptr, nxt2);
    // K5: recon level 1 -> nxt1 (128x128), reuses cur1's storage
    idwt_kernel<64><<<dim3(NB * NC * 64 * 64 / 256), 256, 0, stream>>>(t1, nxt2, nxt1);
    // K6: base conv + level-0 dwt/conv/idwt + y (fp32 into d_out) + partials
    final_fuse_kernel<<<dim3(16, NC, NB), 256, 0, stream>>>(x, nxt1, bw, bb, bs, ww0, ws0, yb, partials);
    // K7: BN stats
    stats_kernel<<<dim3(64), 256, 0, stream>>>(partials, gamma, beta, ab);
    // K8: normalize + relu in place
    norm_inplace_kernel<<<dim3(2048), 256, 0, stream>>>(yb, ab);
}

// Round 6
// 363.559 us; speedup vs baseline: 1.5804x; 1.3349x over previous
//
#include <hip/hip_runtime.h>
#include <hip/hip_bf16.h>

#define NB 16
#define NC 64

static __device__ __forceinline__ unsigned short f2bfr(float f) {
    union { float f; unsigned u; } cv; cv.f = f;
    unsigned r = cv.u + 0x7fffu + ((cv.u >> 16) & 1u);
    return (unsigned short)(r >> 16);
}
static __device__ __forceinline__ float bfr2f(unsigned short h) {
    union { unsigned u; float f; } cv; cv.u = ((unsigned)h) << 16;
    return cv.f;
}

// ---------------------------------------------------------------------------
// Shift-addressed float4 staging of a 68x72 halo tile (global start row sTop,
// col sLeft; sLeft is 4-aligned). Zero-fills out-of-range float4s.
// ---------------------------------------------------------------------------
template <int H>
static __device__ __forceinline__ void stage_tile(
    const float* __restrict__ src, size_t ibase, int sTop, int sLeft,
    float (*sIn)[72], int tid)
{
#pragma unroll
    for (int i = 0; i < 5; ++i) {
        int idx = i * 256 + tid;
        if (idx < 68 * 16) {
            int r = idx >> 4, c4 = (idx & 15) << 2;
            int gy = sTop + r, gx = sLeft + c4;
            float4 v = make_float4(0.f, 0.f, 0.f, 0.f);
            if ((unsigned)gy < (unsigned)H && (unsigned)gx < (unsigned)H)
                v = *(const float4*)(src + ibase + (size_t)gy * H + gx);
            *(float4*)(&sIn[r][c4]) = v;
        }
    }
    if (tid < 136) {
        int r = tid >> 1, c4 = 64 + ((tid & 1) << 2);
        int gy = sTop + r, gx = sLeft + c4;
        float4 v = make_float4(0.f, 0.f, 0.f, 0.f);
        if ((unsigned)gy < (unsigned)H && (unsigned)gx < (unsigned)H)
            v = *(const float4*)(src + ibase + (size_t)gy * H + gx);
        *(float4*)(&sIn[r][c4]) = v;
    }
}

// ---------------------------------------------------------------------------
// K1: LL band of Haar DWT of x: (B,C,256,256) -> (B,C,128,128). Pure stream.
// ---------------------------------------------------------------------------
__global__ __launch_bounds__(256) void ll_kernel(
    const float* __restrict__ in, float* __restrict__ ll)
{
    int t = blockIdx.x * 256 + threadIdx.x;
    int jp  = t & 63;
    int i   = (t >> 6) & 127;
    int img = t >> 13;
    size_t ib = (size_t)img * 65536;
    float4 a = *(const float4*)(in + ib + (size_t)(2 * i) * 256 + 4 * jp);
    float4 b = *(const float4*)(in + ib + (size_t)(2 * i + 1) * 256 + 4 * jp);
    float2 o;
    o.x = 0.5f * (a.x + a.y + b.x + b.y);
    o.y = 0.5f * (a.z + a.w + b.z + b.w);
    *(float2*)(ll + (size_t)img * 16384 + (size_t)i * 128 + 2 * jp) = o;
}

// ---------------------------------------------------------------------------
// K2/K3: fused Haar DWT + depthwise 3x3 conv (SAME) + scale, register-DWT.
// ---------------------------------------------------------------------------
template <int H>
__global__ __launch_bounds__(256) void dwt_conv_kernel(
    const float* __restrict__ in, const float* __restrict__ ww,
    const float* __restrict__ wsc, float* __restrict__ t_out,
    float* __restrict__ curn)
{
    constexpr int H2 = H / 2;
    constexpr int TX = H2 / 32;
    const int tile = blockIdx.x;
    const int c = blockIdx.y, b = blockIdx.z;
    const int ty = tile / TX, tx = tile % TX;
    const int oy0 = ty * 32, ox0 = tx * 32;
    const int tid = threadIdx.x;

    __shared__ float sIn[68][72];

    float w[4][9], sc[4];
#pragma unroll
    for (int k = 0; k < 4; ++k) {
#pragma unroll
        for (int i = 0; i < 9; ++i) w[k][i] = ww[(c * 4 + k) * 9 + i];
        sc[k] = 0.5f * wsc[c * 4 + k];   // fold DWT 0.5
    }

    const size_t ibase = (size_t)(b * NC + c) * H * H;
    stage_tile<H>(in, ibase, 2 * oy0 - 2, 2 * ox0 - 4, sIn, tid);
    __syncthreads();

    const size_t tbase = (size_t)(b * NC + c) * 4 * H2 * H2;
    const size_t cbase = (size_t)(b * NC + c) * H2 * H2;
    const int qj = tid & 31;
    const int qi0 = tid >> 5;
#pragma unroll
    for (int it = 0; it < 4; ++it) {
        int qi = qi0 + 8 * it;
        float P[6][6];
#pragma unroll
        for (int r = 0; r < 6; ++r) {
            const float2* rp = (const float2*)&sIn[2 * qi + r][2 * qj + 2];
            float2 p0 = rp[0], p1 = rp[1], p2 = rp[2];
            P[r][0] = p0.x; P[r][1] = p0.y; P[r][2] = p1.x;
            P[r][3] = p1.y; P[r][4] = p2.x; P[r][5] = p2.y;
        }
        float kk0 = 0.f, kk1 = 0.f, kk2 = 0.f, kk3 = 0.f, llc = 0.f;
#pragma unroll
        for (int r = 0; r < 3; ++r)
#pragma unroll
            for (int s = 0; s < 3; ++s) {
                float a = P[2*r][2*s],   e = P[2*r][2*s+1];
                float f = P[2*r+1][2*s], g = P[2*r+1][2*s+1];
                float s0 = a + e, s1 = f + g, d0 = a - e, d1 = f - g;
                float b0 = s0 + s1;
                kk0 += w[0][3*r+s] * b0;
                kk1 += w[1][3*r+s] * (s0 - s1);
                kk2 += w[2][3*r+s] * (d0 + d1);
                kk3 += w[3][3*r+s] * (d0 - d1);
                if (r == 1 && s == 1) llc = 0.5f * b0;
            }
        size_t o = (size_t)(oy0 + qi) * H2 + (ox0 + qj);
        t_out[tbase + o]                       = kk0 * sc[0];
        t_out[tbase + (size_t)H2 * H2 + o]     = kk1 * sc[1];
        t_out[tbase + (size_t)2 * H2 * H2 + o] = kk2 * sc[2];
        t_out[tbase + (size_t)3 * H2 * H2 + o] = kk3 * sc[3];
        if (curn) curn[cbase + o] = llc;
    }
}

// ---------------------------------------------------------------------------
// K45: fused two-level reconstruction: idwt(t2) feeding idwt(t1) -> nxt1.
// One thread per level-1 coefficient position (i,j) in 64x64.
// ---------------------------------------------------------------------------
__global__ __launch_bounds__(256) void idwt_fuse_kernel(
    const float* __restrict__ t1, const float* __restrict__ t2,
    float* __restrict__ nxt1)
{
    int idx = blockIdx.x * 256 + threadIdx.x;   // NB*NC*4096
    int j = idx & 63, i = (idx >> 6) & 63, img = idx >> 12;
    size_t t2b = (size_t)img * 4096 + (size_t)(i >> 1) * 32 + (j >> 1);
    float m0 = t2[t2b], m1 = t2[t2b + 1024], m2 = t2[t2b + 2048], m3 = t2[t2b + 3072];
    float a1 = (i & 1) ? -m1 : m1;
    float a2 = (j & 1) ? -m2 : m2;
    float a3 = ((i ^ j) & 1) ? -m3 : m3;
    float nxt2v = 0.5f * (m0 + a1 + a2 + a3);
    size_t t1b = (size_t)img * 16384 + (size_t)i * 64 + j;
    float k0 = t1[t1b] + nxt2v;
    float k1 = t1[t1b + 4096], k2 = t1[t1b + 8192], k3 = t1[t1b + 12288];
    size_t ob = (size_t)img * 16384 + (size_t)(2 * i) * 128 + 2 * j;
    *(float2*)(nxt1 + ob) = make_float2(0.5f * (k0 + k1 + k2 + k3),
                                        0.5f * (k0 + k1 - k2 - k3));
    *(float2*)(nxt1 + ob + 128) = make_float2(0.5f * (k0 - k1 + k2 - k3),
                                              0.5f * (k0 - k1 - k2 + k3));
}

// ---------------------------------------------------------------------------
// K6: final fuse. Register DWT -> band convs -> IDWT + base conv; writes
// unnormalized y as bf16 to workspace + deterministic BN partials.
// ---------------------------------------------------------------------------
__global__ __launch_bounds__(256) void final_fuse_kernel(
    const float* __restrict__ x, const float* __restrict__ nxt1,
    const float* __restrict__ bw, const float* __restrict__ bb,
    const float* __restrict__ bs, const float* __restrict__ ww0,
    const float* __restrict__ ws0,
    unsigned short* __restrict__ ybf, float2* __restrict__ partials)
{
    const int tile = blockIdx.x, c = blockIdx.y, b = blockIdx.z;
    const int ty = tile >> 2, tx = tile & 3;
    const int oy0 = ty * 64, ox0 = tx * 64;
    const int hy0 = ty * 32, hx0 = tx * 32;
    const int tid = threadIdx.x;

    __shared__ float sIn[68][72];
    __shared__ float rS[256], rQ[256];

    float w[4][9], sc[4], wb[9];
#pragma unroll
    for (int k = 0; k < 4; ++k) {
#pragma unroll
        for (int i = 0; i < 9; ++i) w[k][i] = ww0[(c * 4 + k) * 9 + i];
        sc[k] = 0.25f * ws0[c * 4 + k];   // fold DWT 0.5 AND IDWT 0.5
    }
#pragma unroll
    for (int i = 0; i < 9; ++i) wb[i] = bw[c * 9 + i];
    const float scale = bs[c];
    const float bsc = bb[c] * scale;

    const size_t xb = (size_t)(b * NC + c) * 65536;
    stage_tile<256>(x, xb, oy0 - 2, ox0 - 4, sIn, tid);
    __syncthreads();

    const size_t n1b = (size_t)(b * NC + c) * 16384;
    const int qj = tid & 31;
    const int qi0 = tid >> 5;
    float lsum = 0.f, lss = 0.f;
#pragma unroll
    for (int it = 0; it < 4; ++it) {
        int qi = qi0 + 8 * it;
        float P[6][6];
#pragma unroll
        for (int r = 0; r < 6; ++r) {
            const float2* rp = (const float2*)&sIn[2 * qi + r][2 * qj + 2];
            float2 p0 = rp[0], p1 = rp[1], p2 = rp[2];
            P[r][0] = p0.x; P[r][1] = p0.y; P[r][2] = p1.x;
            P[r][3] = p1.y; P[r][4] = p2.x; P[r][5] = p2.y;
        }
        float kk0 = 0.f, kk1 = 0.f, kk2 = 0.f, kk3 = 0.f;
#pragma unroll
        for (int r = 0; r < 3; ++r)
#pragma unroll
            for (int s = 0; s < 3; ++s) {
                float a = P[2*r][2*s],   e = P[2*r][2*s+1];
                float f = P[2*r+1][2*s], g = P[2*r+1][2*s+1];
                float s0 = a + e, s1 = f + g, d0 = a - e, d1 = f - g;
                kk0 += w[0][3*r+s] * (s0 + s1);
                kk1 += w[1][3*r+s] * (s0 - s1);
                kk2 += w[2][3*r+s] * (d0 + d1);
                kk3 += w[3][3*r+s] * (d0 - d1);
            }
        kk0 = kk0 * sc[0] + 0.5f * nxt1[n1b + (size_t)(hy0 + qi) * 128 + (hx0 + qj)];
        kk1 *= sc[1];
        kk2 *= sc[2];
        kk3 *= sc[3];
        float vv[2][2];
        vv[0][0] = kk0 + kk1 + kk2 + kk3;
        vv[0][1] = kk0 + kk1 - kk2 - kk3;
        vv[1][0] = kk0 - kk1 + kk2 - kk3;
        vv[1][1] = kk0 - kk1 - kk2 + kk3;
        int yl = 2 * qi, xl = 2 * qj;
#pragma unroll
        for (int p = 0; p < 2; ++p) {
            unsigned pack = 0;
#pragma unroll
            for (int q = 0; q < 2; ++q) {
                float acc = 0.f;
#pragma unroll
                for (int r = 0; r < 3; ++r)
#pragma unroll
                    for (int s = 0; s < 3; ++s)
                        acc += P[p + r + 1][q + s + 1] * wb[3 * r + s];
                float val = fmaf(acc, scale, bsc) + vv[p][q];
                lsum += val;
                lss = fmaf(val, val, lss);
                pack |= ((unsigned)f2bfr(val)) << (16 * q);
            }
            *(unsigned*)(ybf + xb + (size_t)(oy0 + yl + p) * 256 + (ox0 + xl)) = pack;
        }
    }
    rS[tid] = lsum;
    rQ[tid] = lss;
    __syncthreads();
    for (int off = 128; off > 0; off >>= 1) {
        if (tid < off) { rS[tid] += rS[tid + off]; rQ[tid] += rQ[tid + off]; }
        __syncthreads();
    }
    if (tid == 0)
        partials[c * 256 + b * 16 + tile] = make_float2(rS[0], rQ[0]);
}

// ---------------------------------------------------------------------------
// K7: per-channel BN stats -> (a,b). 64 blocks x 256 threads.
// ---------------------------------------------------------------------------
__global__ __launch_bounds__(256) void stats_kernel(
    const float2* __restrict__ partials, const float* __restrict__ gamma,
    const float* __restrict__ beta, float2* __restrict__ ab)
{
    const int c = blockIdx.x;
    const int tid = threadIdx.x;
    __shared__ float s1[256], s2[256];
    float2 p = partials[c * 256 + tid];
    s1[tid] = p.x;
    s2[tid] = p.y;
    __syncthreads();
    for (int off = 128; off > 0; off >>= 1) {
        if (tid < off) { s1[tid] += s1[tid + off]; s2[tid] += s2[tid + off]; }
        __syncthreads();
    }
    if (tid == 0) {
        const float N = (float)NB * 65536.0f;
        float mean = s1[0] / N;
        float var = s2[0] / N - mean * mean;
        float inv = rsqrtf(var + 1e-5f);
        float a = gamma[c] * inv;
        ab[c] = make_float2(a, beta[c] - mean * a);
    }
}

// ---------------------------------------------------------------------------
// K8: normalize + ReLU: bf16 y-staging -> fp32 d_out. 8 elems per iter.
// Explicit member writes (NO cross-local pointer arithmetic).
// ---------------------------------------------------------------------------
__global__ __launch_bounds__(256) void norm_out_kernel(
    const unsigned short* __restrict__ ybf, const float2* __restrict__ ab,
    float* __restrict__ out)
{
    const long total8 = (long)NB * NC * 65536 / 8;
    const long stride = (long)gridDim.x * 256;
    for (long i = blockIdx.x * 256L + threadIdx.x; i < total8; i += stride) {
        long e = i * 8;
        int c = (int)((e >> 16) & (NC - 1));
        float2 s = ab[c];
        uint4 v = *(const uint4*)(ybf + e);
        float4 o0, o1;
        o0.x = fmaxf(fmaf(bfr2f((unsigned short)(v.x & 0xffff)), s.x, s.y), 0.f);
        o0.y = fmaxf(fmaf(bfr2f((unsigned short)(v.x >> 16)),    s.x, s.y), 0.f);
        o0.z = fmaxf(fmaf(bfr2f((unsigned short)(v.y & 0xffff)), s.x, s.y), 0.f);
        o0.w = fmaxf(fmaf(bfr2f((unsigned short)(v.y >> 16)),    s.x, s.y), 0.f);
        o1.x = fmaxf(fmaf(bfr2f((unsigned short)(v.z & 0xffff)), s.x, s.y), 0.f);
        o1.y = fmaxf(fmaf(bfr2f((unsigned short)(v.z >> 16)),    s.x, s.y), 0.f);
        o1.z = fmaxf(fmaf(bfr2f((unsigned short)(v.w & 0xffff)), s.x, s.y), 0.f);
        o1.w = fmaxf(fmaf(bfr2f((unsigned short)(v.w >> 16)),    s.x, s.y), 0.f);
        *(float4*)(out + e) = o0;
        *(float4*)(out + e + 4) = o1;
    }
}

extern "C" void kernel_launch(void* const* d_in, const int* in_sizes, int n_in,
                              void* d_out, int out_size, void* d_ws, size_t ws_size,
                              hipStream_t stream)
{
    const float* x    = (const float*)d_in[0];
    const float* bw   = (const float*)d_in[1];
    const float* bb   = (const float*)d_in[2];
    const float* bs   = (const float*)d_in[3];
    const float* ww0  = (const float*)d_in[4];
    const float* ww1  = (const float*)d_in[5];
    const float* ww2  = (const float*)d_in[6];
    const float* ws0  = (const float*)d_in[7];
    const float* ws1  = (const float*)d_in[8];
    const float* ws2  = (const float*)d_in[9];
    const float* gamma = (const float*)d_in[10];
    const float* beta  = (const float*)d_in[11];

    char* w = (char*)d_ws;
    // Layout (bytes). ybf aliases t1/cur2/t2 which are dead before K6 writes it.
    float* cur1 = (float*)(w);                                   // 64 MiB [0, 64M)
    float* t1   = (float*)(w + 67108864);                        // 64 MiB
    float* cur2 = (float*)(w + 67108864 + 67108864);             // 16 MiB
    float* t2   = (float*)(w + 67108864 + 83886080);             // 16 MiB
    unsigned short* ybf = (unsigned short*)(w + 67108864);       // 128 MiB (aliases t1..t2)
    float2* partials = (float2*)(w + 67108864 + 134217728);      // 128 KB
    float2* ab       = (float2*)(w + 67108864 + 134217728 + 131072);
    float* nxt1 = cur1;   // cur1 dead after K2; K45 writes nxt1 here

    // K1: x -> cur1 (LL only)
    ll_kernel<<<dim3(NB * NC * 128 * 64 / 256), 256, 0, stream>>>(x, cur1);
    // K2: level 1
    dwt_conv_kernel<128><<<dim3(4, NC, NB), 256, 0, stream>>>(cur1, ww1, ws1, t1, cur2);
    // K3: level 2
    dwt_conv_kernel<64><<<dim3(1, NC, NB), 256, 0, stream>>>(cur2, ww2, ws2, t2, nullptr);
    // K45: fused recon level2+1 -> nxt1
    idwt_fuse_kernel<<<dim3(NB * NC * 4096 / 256), 256, 0, stream>>>(t1, t2, nxt1);
    // K6: base conv + level-0 dwt/conv/idwt -> ybf (bf16) + partials
    final_fuse_kernel<<<dim3(16, NC, NB), 256, 0, stream>>>(x, nxt1, bw, bb, bs, ww0, ws0, ybf, partials);
    // K7: BN stats
    stats_kernel<<<dim3(64), 256, 0, stream>>>(partials, gamma, beta, ab);
    // K8: normalize + relu -> d_out (fp32)
    norm_out_kernel<<<dim3(2048), 256, 0, stream>>>(ybf, ab, (float*)d_out);
}